// Round 21
// baseline (194.277 us; speedup 1.0000x reference)
//
#include <hip/hip_runtime.h>

#define N_PTS   20000
#define M_ATOMS 10000
#define DAT     64
#define HID     129
#define KNN     16
#define NLAYERS 3

#define A_HSTRIDE  132        // A row stride in HALVES (264 B, 8B-aligned)

#define GRIDL   24
#define NCELL   (GRIDL*GRIDL*GRIDL)   // 13824
#define CELL_H  4.0f
#define INV_H   0.25f
#define GORIG   (-48.0f)

#define A_GROUPS   (M_ATOMS / 8)                  // 1250 (8 atoms/wave)

#define PTS_B  16             // points per fused block
#define PADPE  72             // pe_buf row stride (halves)
#define PADP   148            // P row stride (floats)
#define PADHS  136            // HS row stride (halves); K=128 exact
#define PADMS  68             // MSG row stride (floats), aliased onto P region
#define W1F_HALVES (8 * 144 * 8)    // 9216 per layer
#define W2F_HALVES (16 * 64 * 8)    // 8192 per layer
#define WF_BLK  ((NLAYERS * (W1F_HALVES + W2F_HALVES)) / 512)   // 102 exact
#define PREA_BLK ((NLAYERS * A_GROUPS + 7) / 8)                 // 469

typedef _Float16 half2_t __attribute__((ext_vector_type(2)));
typedef _Float16 f16x8   __attribute__((ext_vector_type(8)));
typedef float    f32x4   __attribute__((ext_vector_type(4)));

__device__ __forceinline__ float readlane_f(float v, int l) {
    return __int_as_float(__builtin_amdgcn_readlane(__float_as_int(v), l));
}
__device__ __forceinline__ int cell_of(float v) {
    int c = (int)floorf((v - GORIG) * INV_H);
    return c < 0 ? 0 : (c > GRIDL - 1 ? GRIDL - 1 : c);
}

// ================= grid build (h=4) =================
__global__ void grid_zero(int* __restrict__ counts) {
    int i = blockIdx.x * 256 + threadIdx.x;
    if (i <= NCELL) counts[i] = 0;
}

__global__ void grid_count(const float* __restrict__ y, int* __restrict__ counts,
                           int* __restrict__ acell) {
    int i = blockIdx.x * 256 + threadIdx.x;
    if (i >= M_ATOMS) return;
    float a = y[3*i], b = y[3*i+1], c = y[3*i+2];
    int cid = (cell_of(c) * GRIDL + cell_of(b)) * GRIDL + cell_of(a);
    acell[i] = cid;
    atomicAdd(&counts[cid], 1);
}

__global__ __launch_bounds__(1024) void grid_scan(const int* __restrict__ counts,
        int* __restrict__ starts, int* __restrict__ cursor) {
    __shared__ int part[1024];
    const int t = threadIdx.x;
    const int base = t * 14;                       // 1024*14 = 14336 >= 13824
    int loc[14]; int sum = 0;
#pragma unroll
    for (int i = 0; i < 14; ++i) {
        int idx = base + i;
        int c = (idx < NCELL) ? counts[idx] : 0;
        loc[i] = sum; sum += c;
    }
    part[t] = sum;
    for (int o = 1; o < 1024; o <<= 1) {
        __syncthreads();
        int v = (t >= o) ? part[t - o] : 0;
        __syncthreads();
        part[t] += v;
    }
    __syncthreads();
    int prev = (t > 0) ? part[t - 1] : 0;
#pragma unroll
    for (int i = 0; i < 14; ++i) {
        int idx = base + i;
        if (idx < NCELL) { int s = prev + loc[i]; starts[idx] = s; cursor[idx] = s; }
    }
    if (t == 1023) starts[NCELL] = part[1023];
}

__global__ void grid_scatter(const float* __restrict__ y, const int* __restrict__ acell,
                             int* __restrict__ cursor, float4* __restrict__ ypc,
                             int* __restrict__ aidx) {
    int i = blockIdx.x * 256 + threadIdx.x;
    if (i >= M_ATOMS) return;
    int cid = acell[i];
    int pos = atomicAdd(&cursor[cid], 1);
    float a = y[3*i], b = y[3*i+1], c = y[3*i+2];
    ypc[pos]  = make_float4(a, b, c, (a*a + b*b) + c*c);   // (y**2).sum(1) order
    aidx[pos] = i;
}

// ================= fat kernel: weight fragments + A-table precompute =================
// blocks 0..101: fragment conversion; blocks 102..570: per-atom A precompute.
__global__ __launch_bounds__(512) void wfrag_pre(
        const float* __restrict__ W1, const float* __restrict__ W2,
        _Float16* __restrict__ w1f, _Float16* __restrict__ w2f,
        const float* __restrict__ feats, const float* __restrict__ b1,
        _Float16* __restrict__ A) {
    const int tid = threadIdx.x;
    if (blockIdx.x < WF_BLK) {
        int i = blockIdx.x * 512 + tid;
        if (i < NLAYERS * W1F_HALVES) {
            int l = i / W1F_HALVES, r = i - l * W1F_HALVES;
            int j = r & 7, v = r >> 3;
            int c = v % 144, kg = v / 144;
            float val = (c < HID) ? W1[(size_t)l * HID * HID + (kg * 8 + j) * HID + c] : 0.f;
            w1f[i] = (_Float16)val;
            return;
        }
        int i2 = i - NLAYERS * W1F_HALVES;
        if (i2 < NLAYERS * W2F_HALVES) {
            int l = i2 / W2F_HALVES, r = i2 - l * W2F_HALVES;
            int j = r & 7, v = r >> 3;
            int c = v & 63, kg = v >> 6;
            w2f[i2] = (_Float16)W2[(size_t)l * HID * DAT + (kg * 8 + j) * DAT + c];
        }
        return;
    }
    // ---------- A precompute: A[l][i] = feats[i] @ W1[l][64:128] + b1[l] (fp16) ----------
    const int wave = tid >> 6, lane = tid & 63;
    int id = (blockIdx.x - WF_BLK) * 8 + wave;
    if (id >= NLAYERS * A_GROUPS) return;
    int l = id / A_GROUPS, g = id - l * A_GROUPS;
    int base_atom = g * 8;

    float f[8];
#pragma unroll
    for (int a = 0; a < 8; ++a) f[a] = feats[(base_atom + a) * DAT + lane];
    float a0[8], a1[8], a2[8];
#pragma unroll
    for (int a = 0; a < 8; ++a) { a0[a] = 0.f; a1[a] = 0.f; a2[a] = 0.f; }

    const float* Wl = W1 + (size_t)l * HID * HID;
#pragma unroll 4
    for (int d = 0; d < DAT; ++d) {
        const float* row = Wl + (64 + d) * HID;
        float w0 = row[2 * lane];
        float w1 = row[2 * lane + 1];
        float w2 = row[128];
#pragma unroll
        for (int a = 0; a < 8; ++a) {
            float s = readlane_f(f[a], d);
            a0[a] += s * w0;
            a1[a] += s * w1;
            a2[a] += s * w2;
        }
    }
    const float* b1l = b1 + l * HID;
    float bb0 = b1l[2 * lane], bb1 = b1l[2 * lane + 1], bb2 = b1l[128];
#pragma unroll
    for (int a = 0; a < 8; ++a) {
        _Float16* Ar = A + ((size_t)l * M_ATOMS + base_atom + a) * A_HSTRIDE;
        half2_t hv; hv.x = (_Float16)(a0[a] + bb0); hv.y = (_Float16)(a1[a] + bb1);
        ((half2_t*)Ar)[lane] = hv;
        if (lane == 0) Ar[128] = (_Float16)(a2[a] + bb2);
    }
}

// ================= top-k primitive =================
__device__ __forceinline__ void topk_process(float d2, int ai, int lane,
        float& Ld, int& Li, float& kth, int& kidx, bool& filled) {
    const float INF = __builtin_inff();
    if (!filled) {                                  // bitonic-sort fill (wave-uniform)
        float v = d2; int ix = ai;
#pragma unroll
        for (int k = 2; k <= 64; k <<= 1)
#pragma unroll
            for (int j = k >> 1; j > 0; j >>= 1) {
                float ov = __shfl_xor(v, j);
                int   oi = __shfl_xor(ix, j);
                bool keepmin = (((lane & k) == 0) == ((lane & j) == 0));
                bool oless   = (ov < v) || (ov == v && oi < ix);
                bool take    = (keepmin == oless);
                v  = take ? ov : v;
                ix = take ? oi : ix;
            }
        Ld = (lane < KNN) ? v : INF;
        Li = (lane < KNN) ? ix : 0x7fffffff;
        kth  = readlane_f(v, 15);
        kidx = __builtin_amdgcn_readlane(ix, 15);
        filled = true;
        return;
    }
    bool adm = (d2 < kth) || (d2 == kth && ai < kidx);
    unsigned long long cand = __ballot(adm);
    if (cand) {
        do {
            int src = __builtin_ctzll(cand);
            cand &= cand - 1;
            float v  = readlane_f(d2, src);
            int   mi = __builtin_amdgcn_readlane(ai, src);
            bool pred = (Ld > v) || (Ld == v && Li > mi);   // lexicographic
            unsigned long long bal = __ballot(pred);
            int ins = __builtin_ctzll(bal);
            float pd = __shfl_up(Ld, 1);
            int   pi = __shfl_up(Li, 1);
            bool atins = (lane == ins);
            float tv = atins ? v  : pd;
            int   ti = atins ? mi : pi;
            Ld = pred ? tv : Ld;
            Li = pred ? ti : Li;
        } while (cand);
        kth  = readlane_f(Ld, 15);
        kidx = __builtin_amdgcn_readlane(Li, 15);
    }
}

// ================= fused kNN + MLP =================
// 512 thr, 16 pts/block. Waves 0..7 run exact kNN for 2 points each
// (results kept in registers, no global round-trip), then the block runs
// the verified MFMA mlp phase. Early blocks start MFMA work while straggler
// blocks still scan shells -> knn tail and mlp ramp overlap.
__global__ __launch_bounds__(512) void knn_mlp(
        const float* __restrict__ x, const float* __restrict__ y,
        const int* __restrict__ starts, const float4* __restrict__ ypc,
        const int* __restrict__ aidx,
        const float* __restrict__ W1, const float* __restrict__ W2,
        const float* __restrict__ b2, const float* __restrict__ gnw,
        const float* __restrict__ gnb, const _Float16* __restrict__ A,
        const _Float16* __restrict__ w1fg, const _Float16* __restrict__ w2fg,
        float* __restrict__ out) {
    __shared__ int s_start[8][64];
    __shared__ int s_off[8][64];
    __shared__ __align__(16) _Float16 pe_buf[PTS_B * PADPE];   // 2,304 B
    __shared__ float Pms[PTS_B * PADP];                        // 9,472 B (P, then MSG)
    __shared__ __align__(16) _Float16 hs_lds[PTS_B * PADHS];   // 4,352 B
    __shared__ float hs2_lds[PTS_B];                           // 64 B
    const int tid  = threadIdx.x;
    const int wave = tid >> 6, lane = tid & 63;
    const int lr = lane & 15, lg = lane >> 4;
    const int nb = blockIdx.x * PTS_B;                         // 1250*16 == 20000
    const float INF = __builtin_inff();

    // ---------------- kNN phase: 2 points per wave, sequential ----------------
    int   ikr[2]; float dkr[2];
    for (int p = 0; p < 2; ++p) {
        const int n = nb + wave * 2 + p;
        const float qx = x[3*n], qy = x[3*n+1], qz = x[3*n+2];
        const float qs = (qx*qx + qy*qy) + qz*qz;   // (x**2).sum(1) order
        const int cx = cell_of(qx), cy = cell_of(qy), cz = cell_of(qz);

        float Ld = INF; int Li = 0x7fffffff;
        float kth = INF; int kidx = 0x7fffffff;
        bool filled = false;

        // rings 0..1: 9 contiguous x-runs, serial, center row first
        {
            int sS = 0, cnt = 0;
            if (lane < 9) {
                int dyv = lane % 3 - 1, dzv = lane / 3 - 1;
                int ny = cy + dyv, nz = cz + dzv;
                if (ny >= 0 && ny < GRIDL && nz >= 0 && nz < GRIDL) {
                    int xl = max(cx - 1, 0), xh = min(cx + 1, GRIDL - 1);
                    int cid0 = (nz * GRIDL + ny) * GRIDL + xl;
                    sS  = starts[cid0];
                    cnt = starts[cid0 + (xh - xl) + 1] - sS;
                }
            }
#pragma unroll
            for (int si = 0; si < 9; ++si) {
                const int s = (si == 0) ? 4 : (si <= 4 ? si - 1 : si);  // center first
                const int ss = __builtin_amdgcn_readlane(sS, s);
                const int cc = __builtin_amdgcn_readlane(cnt, s);
                for (int b = 0; b < cc; b += 64) {
                    int pos = b + lane; bool val = pos < cc;
                    int a = val ? (ss + pos) : ss;
                    float4 av = ypc[a];
                    int    ai = aidx[a];
                    float dot = (qx * av.x + qy * av.y) + qz * av.z;
                    float d2  = (qs - 2.f * dot) + av.w;   // same algebra as reference
                    if (!val) { d2 = INF; ai = 0x7fffffff; }
                    topk_process(d2, ai, lane, Ld, Li, kth, kidx, filled);
                }
            }
        }

        // shells r>=2 (rare): lane-parallel segments + binary search
        int R = 1;
        while (R < GRIDL) {
            float bnd = (float)R * CELL_H - 0.125f;     // margin covers d2 rounding
            if (bnd * bnd > kth) break;                 // wave-uniform
            const int r  = R + 1;
            const int n1 = 2 * r + 1, m = 2 * r - 1;
            const int C1 = 2 * n1, C2 = 2 * m;
            const int S  = C1 + C2 + 2 * m * m;
            for (int base = 0; base < S; base += 64) {
                int sid = base + lane;
                int sS = 0, cnt = 0;
                if (sid < S) {
                    int dy, dz, xlo, xhi;
                    if (sid < C1) {
                        dz = (sid < n1) ? -r : r;
                        dy = (sid - ((sid < n1) ? 0 : n1)) - r;
                        xlo = cx - r; xhi = cx + r;
                    } else if (sid < C1 + C2) {
                        int i = sid - C1;
                        dy = (i < m) ? -r : r;
                        dz = (i - ((i < m) ? 0 : m)) - (r - 1);
                        xlo = cx - r; xhi = cx + r;
                    } else {
                        int i = sid - C1 - C2;
                        int pair = i >> 1, side = i & 1;
                        dz = (pair / m) - (r - 1);
                        dy = (pair % m) - (r - 1);
                        int xx = side ? cx + r : cx - r;
                        xlo = xx; xhi = xx;
                    }
                    int ny = cy + dy, nz = cz + dz;
                    if (ny >= 0 && ny < GRIDL && nz >= 0 && nz < GRIDL) {
                        int xl = max(xlo, 0), xh = min(xhi, GRIDL - 1);
                        if (xl <= xh) {
                            int cid0 = (nz * GRIDL + ny) * GRIDL + xl;
                            sS  = starts[cid0];
                            cnt = starts[cid0 + (xh - xl) + 1] - sS;
                        }
                    }
                }
                int incl = cnt;
#pragma unroll
                for (int o = 1; o < 64; o <<= 1) {
                    int v = __shfl_up(incl, o);
                    if (lane >= o) incl += v;
                }
                const int T = __builtin_amdgcn_readlane(incl, 63);
                if (T == 0) continue;
                s_start[wave][lane] = sS;
                s_off[wave][lane]   = incl - cnt;
                for (int b = 0; b < T; b += 64) {
                    int pos = b + lane; bool val = pos < T;
                    int c = 0;
                    c += (s_off[wave][c + 32] <= pos) ? 32 : 0;
                    c += (s_off[wave][c + 16] <= pos) ? 16 : 0;
                    c += (s_off[wave][c + 8]  <= pos) ? 8  : 0;
                    c += (s_off[wave][c + 4]  <= pos) ? 4  : 0;
                    c += (s_off[wave][c + 2]  <= pos) ? 2  : 0;
                    c += (s_off[wave][c + 1]  <= pos) ? 1  : 0;
                    int a = s_start[wave][c] + (pos - s_off[wave][c]);
                    a = val ? a : 0;
                    float4 av = ypc[a];
                    int    ai = aidx[a];
                    float dot = (qx * av.x + qy * av.y) + qz * av.z;
                    float d2  = (qs - 2.f * dot) + av.w;
                    if (!val) { d2 = INF; ai = 0x7fffffff; }
                    topk_process(d2, ai, lane, Ld, Li, kth, kidx, filled);
                }
            }
            R = r;
        }

        // epilogue: exact subtract-form dist, kept in registers (lanes 0..15).
        // GUARD the index: lanes >=16 hold sentinel 0x7fffffff (r20 crash fix).
        int ii = (lane < KNN) ? Li : 0;
        float ax = y[3*ii], ay = y[3*ii+1], az = y[3*ii+2];
        float ddx = qx - ax, ddy = qy - ay, ddz = qz - az;
        ikr[p] = ii;
        dkr[p] = (ddx*ddx + ddy*ddy) + ddz*ddz;     // ((x-y)**2).sum(-1) order
    }

    // init pe_buf, then barrier into mlp phase
    for (int e = tid; e < PTS_B * 64; e += 512)
        pe_buf[(e >> 6) * PADPE + (e & 63)] = (_Float16)1.0f;
    const int ik0 = ikr[0], ik1 = ikr[1];
    const float dk0 = dkr[0], dk1 = dkr[1];
    float pe_res0 = 1.f, pe_res1 = 1.f;
    __syncthreads();

    // ---------------- MLP phase (verified r19 structure) ----------------
    for (int l = 0; l < NLAYERS; ++l) {
        if (l) __syncthreads();                    // GN msg-reads done; pe_buf visible
        const float* Wl  = W1 + (size_t)l * HID * HID;
        const float* W2l = W2 + (size_t)l * HID * DAT;
        const _Float16* Al = A + (size_t)l * M_ATOMS * A_HSTRIDE;

        // issue A-gathers early (latency hidden under MFMA-1)
        half2_t Av0[KNN], Av1[KNN];
#pragma unroll
        for (int k = 0; k < KNN; ++k) {
            int i0 = __builtin_amdgcn_readlane(ik0, k);
            int i1 = __builtin_amdgcn_readlane(ik1, k);
            Av0[k] = ((const half2_t*)(Al + (size_t)i0 * A_HSTRIDE))[lane];
            Av1[k] = ((const half2_t*)(Al + (size_t)i1 * A_HSTRIDE))[lane];
        }
        float A20 = 0.f, A21 = 0.f;
        if (lane < KNN) {
            A20 = (float)Al[(size_t)ik0 * A_HSTRIDE + 128];
            A21 = (float)Al[(size_t)ik1 * A_HSTRIDE + 128];
        }

        // MFMA-1: P[16][129] = pe[16][64] @ W1[0:64][129]  (9 N-tiles x 2 K)
        {
            const f16x8* w1p = (const f16x8*)(w1fg + (size_t)l * W1F_HALVES);
            for (int t = wave; t < 9; t += 8) {
                f32x4 acc = {0.f, 0.f, 0.f, 0.f};
#pragma unroll
                for (int kk = 0; kk < 2; ++kk) {
                    f16x8 a = *(const f16x8*)&pe_buf[lr * PADPE + kk * 32 + lg * 8];
                    f16x8 b = w1p[(kk * 4 + lg) * 144 + t * 16 + lr];
                    acc = __builtin_amdgcn_mfma_f32_16x16x32_f16(a, b, acc, 0, 0, 0);
                }
#pragma unroll
                for (int r = 0; r < 4; ++r)
                    Pms[(lg * 4 + r) * PADP + t * 16 + lr] = acc[r];
            }
        }
        __syncthreads();

        // hsum: wave owns points 2w, 2w+1; lane owns channels (2l, 2l+1)
        {
            const float wl0 = Wl[128 * HID + 2 * lane];
            const float wl1 = Wl[128 * HID + 2 * lane + 1];
            const float wl2 = Wl[128 * HID + 128];
#pragma unroll
            for (int p = 0; p < 2; ++p) {
                const int nl = wave * 2 + p;
                const half2_t* Av = p ? Av1 : Av0;
                const float A2l = p ? A21 : A20;
                const float dkl = p ? dk1 : dk0;
                float2 pp = *(const float2*)&Pms[nl * PADP + 2 * lane];
                float p2  = Pms[nl * PADP + 128];
                float hs0 = 0.f, hs1 = 0.f, hs2 = 0.f;
#pragma unroll
                for (int k = 0; k < KNN; ++k) {
                    float dd = readlane_f(dkl, k);
                    float a2 = readlane_f(A2l, k);
                    float h0 = pp.x + (float)Av[k].x + dd * wl0; hs0 += fmaxf(h0, 0.2f * h0);
                    float h1 = pp.y + (float)Av[k].y + dd * wl1; hs1 += fmaxf(h1, 0.2f * h1);
                    float h2 = p2   + a2             + dd * wl2; hs2 += fmaxf(h2, 0.2f * h2);
                }
                half2_t hv; hv.x = (_Float16)hs0; hv.y = (_Float16)hs1;
                *(half2_t*)&hs_lds[nl * PADHS + 2 * lane] = hv;
                if (lane == 0) hs2_lds[nl] = hs2;
            }
        }
        __syncthreads();

        // MFMA-2: MSG[16][64] = HS[16][128] @ W2[0:128][64]  (4 N-tiles x 4 K; waves 0-3)
        if (wave < 4) {
            const f16x8* w2p = (const f16x8*)(w2fg + (size_t)l * W2F_HALVES);
            f32x4 acc = {0.f, 0.f, 0.f, 0.f};
#pragma unroll
            for (int kk = 0; kk < 4; ++kk) {
                f16x8 a = *(const f16x8*)&hs_lds[lr * PADHS + kk * 32 + lg * 8];
                f16x8 b = w2p[(kk * 4 + lg) * 64 + wave * 16 + lr];
                acc = __builtin_amdgcn_mfma_f32_16x16x32_f16(a, b, acc, 0, 0, 0);
            }
#pragma unroll
            for (int r = 0; r < 4; ++r)
                Pms[(lg * 4 + r) * PADMS + wave * 16 + lr] = acc[r];   // MSG region
        }
        __syncthreads();

        // GroupNorm + leaky + residual: wave owns points 2w, 2w+1; lane = channel
        {
            const float w2c = W2l[128 * DAT + lane];
            const float b2v = 16.f * b2[l * DAT + lane];
            const float gw  = gnw[l * DAT + lane], gb = gnb[l * DAT + lane];
#pragma unroll
            for (int p = 0; p < 2; ++p) {
                const int nl = wave * 2 + p;
                float pe = p ? pe_res1 : pe_res0;
                float m = Pms[nl * PADMS + lane] + hs2_lds[nl] * w2c + b2v;
                float s1 = m;
                s1 += __shfl_xor(s1, 1);  s1 += __shfl_xor(s1, 2);  s1 += __shfl_xor(s1, 4);
                s1 += __shfl_xor(s1, 8);  s1 += __shfl_xor(s1, 16);
                float mu = s1 * (1.f / 32.f);
                float dm = m - mu;
                float s2 = dm * dm;
                s2 += __shfl_xor(s2, 1);  s2 += __shfl_xor(s2, 2);  s2 += __shfl_xor(s2, 4);
                s2 += __shfl_xor(s2, 8);  s2 += __shfl_xor(s2, 16);
                float var = s2 * (1.f / 32.f);
                float g = dm * (1.f / sqrtf(var + 1e-5f)) * gw + gb;
                pe += fmaxf(g, 0.2f * g);
                if (p) pe_res1 = pe; else pe_res0 = pe;
                if (l == NLAYERS - 1) out[(nb + nl) * DAT + lane] = pe;
                else                  pe_buf[nl * PADPE + lane] = (_Float16)pe;
            }
        }
    }
}

// ---------------- launch ----------------
extern "C" void kernel_launch(void* const* d_in, const int* in_sizes, int n_in,
                              void* d_out, int out_size, void* d_ws, size_t ws_size,
                              hipStream_t stream) {
    const float* x     = (const float*)d_in[0];
    const float* y     = (const float*)d_in[1];
    const float* feats = (const float*)d_in[2];
    const float* W1    = (const float*)d_in[3];
    const float* b1    = (const float*)d_in[4];
    const float* W2    = (const float*)d_in[5];
    const float* b2    = (const float*)d_in[6];
    const float* gnw   = (const float*)d_in[7];
    const float* gnb   = (const float*)d_in[8];
    float* out = (float*)d_out;

    char* ws = (char*)d_ws;
    float4*    ypc   = (float4*)  ws;                        // 160,000 B
    _Float16*  A     = (_Float16*)(ws + 160000);             // 7,920,000 B
    int*       starts= (int*)    (ws + 8080000);             // (13824+1)*4
    int*       cursor= (int*)    (ws + 8140000);             // 13824*4
    int*       counts= (int*)    (ws + 8200000);             // (13824+1)*4
    int*       acell = (int*)    (ws + 8260000);             // 10000*4
    int*       aidx  = (int*)    (ws + 8300000);             // 10000*4
    _Float16*  w1fg  = (_Float16*)(ws + 8340000);            // 3*9216*2 = 55,296 B
    _Float16*  w2fg  = (_Float16*)(ws + 8400000);            // 3*8192*2 = 49,152 B
    // total ~8.45 MB of ws

    wfrag_pre   <<<dim3(WF_BLK + PREA_BLK), dim3(512), 0, stream>>>(W1, W2, w1fg, w2fg, feats, b1, A);
    grid_zero   <<<dim3((NCELL + 256) / 256), dim3(256), 0, stream>>>(counts);
    grid_count  <<<dim3((M_ATOMS + 255) / 256), dim3(256), 0, stream>>>(y, counts, acell);
    grid_scan   <<<dim3(1), dim3(1024), 0, stream>>>(counts, starts, cursor);
    grid_scatter<<<dim3((M_ATOMS + 255) / 256), dim3(256), 0, stream>>>(y, acell, cursor, ypc, aidx);
    knn_mlp     <<<dim3(N_PTS / PTS_B), dim3(512), 0, stream>>>(
                    x, y, starts, ypc, aidx, W1, W2, b2, gnw, gnb, A, w1fg, w2fg, out);
}

// Round 22
// 165.809 us; speedup vs baseline: 1.1717x; 1.1717x over previous
//
#include <hip/hip_runtime.h>

#define N_PTS   20000
#define M_ATOMS 10000
#define DAT     64
#define HID     129
#define KNN     16
#define NLAYERS 3

#define A_HSTRIDE  132        // A row stride in HALVES (264 B, 8B-aligned)

#define GRIDL   24
#define NCELL   (GRIDL*GRIDL*GRIDL)   // 13824
#define CELL_H  4.0f
#define INV_H   0.25f
#define GORIG   (-48.0f)

#define KNN_NBLK   (N_PTS / 4)                    // 5000
#define A_GROUPS   (M_ATOMS / 8)                  // 1250 (8 atoms/wave)
#define PRE_NBLK   ((NLAYERS * A_GROUPS + 3) / 4) // 938

#define PTS_B  16             // points per mlp block
#define PADPE  72             // pe_buf row stride (halves)
#define PADP   148            // P row stride (floats); MFMA-1 writes cols 0..143
#define PADHS  136            // HS row stride (halves); K=128 exact
#define PADMS  68             // MSG row stride (floats), aliased onto P region
#define W1F_HALVES (8 * 144 * 8)    // 9216 per layer
#define W2F_HALVES (16 * 64 * 8)    // 8192 per layer

typedef _Float16 half2_t __attribute__((ext_vector_type(2)));
typedef _Float16 f16x8   __attribute__((ext_vector_type(8)));
typedef float    f32x4   __attribute__((ext_vector_type(4)));

__device__ __forceinline__ float readlane_f(float v, int l) {
    return __int_as_float(__builtin_amdgcn_readlane(__float_as_int(v), l));
}
__device__ __forceinline__ int cell_of(float v) {
    int c = (int)floorf((v - GORIG) * INV_H);
    return c < 0 ? 0 : (c > GRIDL - 1 ? GRIDL - 1 : c);
}

// ================= grid build (h=4) =================
__global__ void grid_zero(int* __restrict__ counts) {
    int i = blockIdx.x * 256 + threadIdx.x;
    if (i <= NCELL) counts[i] = 0;
}

__global__ void grid_count(const float* __restrict__ y, int* __restrict__ counts,
                           int* __restrict__ acell) {
    int i = blockIdx.x * 256 + threadIdx.x;
    if (i >= M_ATOMS) return;
    float a = y[3*i], b = y[3*i+1], c = y[3*i+2];
    int cid = (cell_of(c) * GRIDL + cell_of(b)) * GRIDL + cell_of(a);
    acell[i] = cid;
    atomicAdd(&counts[cid], 1);
}

__global__ __launch_bounds__(1024) void grid_scan(const int* __restrict__ counts,
        int* __restrict__ starts, int* __restrict__ cursor) {
    __shared__ int part[1024];
    const int t = threadIdx.x;
    const int base = t * 14;                       // 1024*14 = 14336 >= 13824
    int loc[14]; int sum = 0;
#pragma unroll
    for (int i = 0; i < 14; ++i) {
        int idx = base + i;
        int c = (idx < NCELL) ? counts[idx] : 0;
        loc[i] = sum; sum += c;
    }
    part[t] = sum;
    for (int o = 1; o < 1024; o <<= 1) {
        __syncthreads();
        int v = (t >= o) ? part[t - o] : 0;
        __syncthreads();
        part[t] += v;
    }
    __syncthreads();
    int prev = (t > 0) ? part[t - 1] : 0;
#pragma unroll
    for (int i = 0; i < 14; ++i) {
        int idx = base + i;
        if (idx < NCELL) { int s = prev + loc[i]; starts[idx] = s; cursor[idx] = s; }
    }
    if (t == 1023) starts[NCELL] = part[1023];
}

__global__ void grid_scatter(const float* __restrict__ y, const int* __restrict__ acell,
                             int* __restrict__ cursor, float4* __restrict__ ypc,
                             int* __restrict__ aidx) {
    int i = blockIdx.x * 256 + threadIdx.x;
    if (i >= M_ATOMS) return;
    int cid = acell[i];
    int pos = atomicAdd(&cursor[cid], 1);
    float a = y[3*i], b = y[3*i+1], c = y[3*i+2];
    ypc[pos]  = make_float4(a, b, c, (a*a + b*b) + c*c);   // (y**2).sum(1) order
    aidx[pos] = i;
}

// ================= weight fragment pre-conversion (once) =================
// w1f[l][(kg*144 + c)*8 + j] = f16(W1[l][kg*8+j][c])   kg 0..7, c<129 (pad 0)
// w2f[l][(kg*64  + c)*8 + j] = f16(W2[l][kg*8+j][c])   kg 0..15, K=128 exact
__global__ void wfrag_kernel(const float* __restrict__ W1, const float* __restrict__ W2,
                             _Float16* __restrict__ w1f, _Float16* __restrict__ w2f) {
    int i = blockIdx.x * 512 + threadIdx.x;
    if (i < NLAYERS * W1F_HALVES) {
        int l = i / W1F_HALVES, r = i - l * W1F_HALVES;
        int j = r & 7, v = r >> 3;
        int c = v % 144, kg = v / 144;
        float val = (c < HID) ? W1[(size_t)l * HID * HID + (kg * 8 + j) * HID + c] : 0.f;
        w1f[i] = (_Float16)val;
        return;
    }
    int i2 = i - NLAYERS * W1F_HALVES;
    if (i2 < NLAYERS * W2F_HALVES) {
        int l = i2 / W2F_HALVES, r = i2 - l * W2F_HALVES;
        int j = r & 7, v = r >> 3;
        int c = v & 63, kg = v >> 6;
        w2f[i2] = (_Float16)W2[(size_t)l * HID * DAT + (kg * 8 + j) * DAT + c];
    }
}

// ================= top-k primitive =================
__device__ __forceinline__ void topk_process(float d2, int ai, int lane,
        float& Ld, int& Li, float& kth, int& kidx, bool& filled) {
    const float INF = __builtin_inff();
    if (!filled) {                                  // bitonic-sort fill (wave-uniform)
        float v = d2; int ix = ai;
#pragma unroll
        for (int k = 2; k <= 64; k <<= 1)
#pragma unroll
            for (int j = k >> 1; j > 0; j >>= 1) {
                float ov = __shfl_xor(v, j);
                int   oi = __shfl_xor(ix, j);
                bool keepmin = (((lane & k) == 0) == ((lane & j) == 0));
                bool oless   = (ov < v) || (ov == v && oi < ix);
                bool take    = (keepmin == oless);
                v  = take ? ov : v;
                ix = take ? oi : ix;
            }
        Ld = (lane < KNN) ? v : INF;
        Li = (lane < KNN) ? ix : 0x7fffffff;
        kth  = readlane_f(v, 15);
        kidx = __builtin_amdgcn_readlane(ix, 15);
        filled = true;
        return;
    }
    bool adm = (d2 < kth) || (d2 == kth && ai < kidx);
    unsigned long long cand = __ballot(adm);
    if (cand) {
        do {
            int src = __builtin_ctzll(cand);
            cand &= cand - 1;
            float v  = readlane_f(d2, src);
            int   mi = __builtin_amdgcn_readlane(ai, src);
            bool pred = (Ld > v) || (Ld == v && Li > mi);   // lexicographic
            unsigned long long bal = __ballot(pred);
            int ins = __builtin_ctzll(bal);
            float pd = __shfl_up(Ld, 1);
            int   pi = __shfl_up(Li, 1);
            bool atins = (lane == ins);
            float tv = atins ? v  : pd;
            int   ti = atins ? mi : pi;
            Ld = pred ? tv : Ld;
            Li = pred ? ti : Li;
        } while (cand);
        kth  = readlane_f(Ld, 15);
        kidx = __builtin_amdgcn_readlane(Li, 15);
    }
}

// ================= fat kernel: knn query (blocks 0..4999) + A precompute =================
__global__ __launch_bounds__(256) void knn_pre(
        const float* __restrict__ x, const float* __restrict__ y,
        const int* __restrict__ starts, const float4* __restrict__ ypc,
        const int* __restrict__ aidx,
        int* __restrict__ oidx, float* __restrict__ odist,
        const float* __restrict__ feats, const float* __restrict__ W1,
        const float* __restrict__ b1, _Float16* __restrict__ A) {
    __shared__ int s_start[4][64];
    __shared__ int s_off[4][64];
    const int lane = threadIdx.x & 63;
    const int wid  = threadIdx.x >> 6;

    if (blockIdx.x >= KNN_NBLK) {
        // ---------- per-atom precompute: A[l][i] = feats[i] @ W1[l][64:128] + b1[l] (fp16) ----------
        int id = (blockIdx.x - KNN_NBLK) * 4 + wid;
        if (id >= NLAYERS * A_GROUPS) return;
        int l = id / A_GROUPS, g = id - l * A_GROUPS;
        int base_atom = g * 8;

        float f[8];
#pragma unroll
        for (int a = 0; a < 8; ++a) f[a] = feats[(base_atom + a) * DAT + lane];
        float a0[8], a1[8], a2[8];
#pragma unroll
        for (int a = 0; a < 8; ++a) { a0[a] = 0.f; a1[a] = 0.f; a2[a] = 0.f; }

        const float* Wl = W1 + (size_t)l * HID * HID;
#pragma unroll 4
        for (int d = 0; d < DAT; ++d) {
            const float* row = Wl + (64 + d) * HID;
            float w0 = row[2 * lane];
            float w1 = row[2 * lane + 1];
            float w2 = row[128];
#pragma unroll
            for (int a = 0; a < 8; ++a) {
                float s = readlane_f(f[a], d);
                a0[a] += s * w0;
                a1[a] += s * w1;
                a2[a] += s * w2;
            }
        }
        const float* b1l = b1 + l * HID;
        float bb0 = b1l[2 * lane], bb1 = b1l[2 * lane + 1], bb2 = b1l[128];
#pragma unroll
        for (int a = 0; a < 8; ++a) {
            _Float16* Ar = A + ((size_t)l * M_ATOMS + base_atom + a) * A_HSTRIDE;
            half2_t hv; hv.x = (_Float16)(a0[a] + bb0); hv.y = (_Float16)(a1[a] + bb1);
            ((half2_t*)Ar)[lane] = hv;
            if (lane == 0) Ar[128] = (_Float16)(a2[a] + bb2);
        }
        return;
    }

    // ---------- kNN query ----------
    const int n = blockIdx.x * 4 + wid;             // < 20000
    const float INF = __builtin_inff();

    const float qx = x[3*n], qy = x[3*n+1], qz = x[3*n+2];
    const float qs = (qx*qx + qy*qy) + qz*qz;       // (x**2).sum(1) order
    const int cx = cell_of(qx), cy = cell_of(qy), cz = cell_of(qz);

    float Ld = INF; int Li = 0x7fffffff;
    float kth = INF; int kidx = 0x7fffffff;
    bool filled = false;

    // rings 0..1: 9 contiguous x-runs, serial, center row first
    {
        int sS = 0, cnt = 0;
        if (lane < 9) {
            int dyv = lane % 3 - 1, dzv = lane / 3 - 1;
            int ny = cy + dyv, nz = cz + dzv;
            if (ny >= 0 && ny < GRIDL && nz >= 0 && nz < GRIDL) {
                int xl = max(cx - 1, 0), xh = min(cx + 1, GRIDL - 1);
                int cid0 = (nz * GRIDL + ny) * GRIDL + xl;
                sS  = starts[cid0];
                cnt = starts[cid0 + (xh - xl) + 1] - sS;
            }
        }
#pragma unroll
        for (int si = 0; si < 9; ++si) {
            const int s = (si == 0) ? 4 : (si <= 4 ? si - 1 : si);  // {4,0,1,2,3,5,6,7,8}
            const int ss = __builtin_amdgcn_readlane(sS, s);
            const int cc = __builtin_amdgcn_readlane(cnt, s);
            for (int b = 0; b < cc; b += 64) {
                int pos = b + lane; bool val = pos < cc;
                int a = val ? (ss + pos) : ss;
                float4 av = ypc[a];
                int    ai = aidx[a];
                float dot = (qx * av.x + qy * av.y) + qz * av.z;
                float d2  = (qs - 2.f * dot) + av.w;   // same algebra as reference
                if (!val) { d2 = INF; ai = 0x7fffffff; }
                topk_process(d2, ai, lane, Ld, Li, kth, kidx, filled);
            }
        }
    }

    // shells r>=2 (rare): lane-parallel segments + binary search
    int R = 1;
    while (R < GRIDL) {
        float bnd = (float)R * CELL_H - 0.125f;     // margin covers d2 rounding
        if (bnd * bnd > kth) break;                 // wave-uniform
        const int r  = R + 1;
        const int n1 = 2 * r + 1, m = 2 * r - 1;
        const int C1 = 2 * n1, C2 = 2 * m;
        const int S  = C1 + C2 + 2 * m * m;
        for (int base = 0; base < S; base += 64) {
            int sid = base + lane;
            int sS = 0, cnt = 0;
            if (sid < S) {
                int dy, dz, xlo, xhi;
                if (sid < C1) {
                    dz = (sid < n1) ? -r : r;
                    dy = (sid - ((sid < n1) ? 0 : n1)) - r;
                    xlo = cx - r; xhi = cx + r;
                } else if (sid < C1 + C2) {
                    int i = sid - C1;
                    dy = (i < m) ? -r : r;
                    dz = (i - ((i < m) ? 0 : m)) - (r - 1);
                    xlo = cx - r; xhi = cx + r;
                } else {
                    int i = sid - C1 - C2;
                    int pair = i >> 1, side = i & 1;
                    dz = (pair / m) - (r - 1);
                    dy = (pair % m) - (r - 1);
                    int xx = side ? cx + r : cx - r;
                    xlo = xx; xhi = xx;
                }
                int ny = cy + dy, nz = cz + dz;
                if (ny >= 0 && ny < GRIDL && nz >= 0 && nz < GRIDL) {
                    int xl = max(xlo, 0), xh = min(xhi, GRIDL - 1);
                    if (xl <= xh) {
                        int cid0 = (nz * GRIDL + ny) * GRIDL + xl;
                        sS  = starts[cid0];
                        cnt = starts[cid0 + (xh - xl) + 1] - sS;
                    }
                }
            }
            int incl = cnt;
#pragma unroll
            for (int o = 1; o < 64; o <<= 1) {
                int v = __shfl_up(incl, o);
                if (lane >= o) incl += v;
            }
            const int T = __builtin_amdgcn_readlane(incl, 63);
            if (T == 0) continue;
            s_start[wid][lane] = sS;
            s_off[wid][lane]   = incl - cnt;
            for (int b = 0; b < T; b += 64) {
                int pos = b + lane; bool val = pos < T;
                int c = 0;
                c += (s_off[wid][c + 32] <= pos) ? 32 : 0;
                c += (s_off[wid][c + 16] <= pos) ? 16 : 0;
                c += (s_off[wid][c + 8]  <= pos) ? 8  : 0;
                c += (s_off[wid][c + 4]  <= pos) ? 4  : 0;
                c += (s_off[wid][c + 2]  <= pos) ? 2  : 0;
                c += (s_off[wid][c + 1]  <= pos) ? 1  : 0;
                int a = s_start[wid][c] + (pos - s_off[wid][c]);
                a = val ? a : 0;
                float4 av = ypc[a];
                int    ai = aidx[a];
                float dot = (qx * av.x + qy * av.y) + qz * av.z;
                float d2  = (qs - 2.f * dot) + av.w;
                if (!val) { d2 = INF; ai = 0x7fffffff; }
                topk_process(d2, ai, lane, Ld, Li, kth, kidx, filled);
            }
        }
        R = r;
    }

    if (lane < KNN) {
        int ii = Li;
        float ax = y[3*ii], ay = y[3*ii+1], az = y[3*ii+2];
        float ddx = qx - ax, ddy = qy - ay, ddz = qz - az;
        float dist = (ddx*ddx + ddy*ddy) + ddz*ddz;   // ((x-y)**2).sum(-1) order
        oidx [n * KNN + lane] = ii;
        odist[n * KNN + lane] = dist;
    }
}

// ================= fused 3-layer MLP: MFMA with global fragment weights =================
// 16 pts/block, 512 thr. B-operands read directly from pre-converted global
// fragment arrays (L2-resident, shared by all blocks) — no per-block staging.
// MFMA-2 is K=128 exact; k=128 channel handled as scalar hs2*w2c in GN phase.
// MSG aliased onto P region (barrier-separated). LDS ~16.2 KB -> 4 blocks/CU.
__global__ __launch_bounds__(512) void mlp_mfma(
        const float* __restrict__ W1, const float* __restrict__ W2,
        const float* __restrict__ b2, const float* __restrict__ gnw,
        const float* __restrict__ gnb, const _Float16* __restrict__ A,
        const _Float16* __restrict__ w1fg, const _Float16* __restrict__ w2fg,
        const int* __restrict__ oidx, const float* __restrict__ odist,
        float* __restrict__ out) {
    __shared__ __align__(16) _Float16 pe_buf[PTS_B * PADPE];   // 2,304 B
    __shared__ float Pms[PTS_B * PADP];                        // 9,472 B (P, then MSG)
    __shared__ __align__(16) _Float16 hs_lds[PTS_B * PADHS];   // 4,352 B
    __shared__ float hs2_lds[PTS_B];                           // 64 B
    const int tid  = threadIdx.x;
    const int wave = tid >> 6, lane = tid & 63;
    const int lr = lane & 15, lg = lane >> 4;
    const int nb = blockIdx.x * PTS_B;                         // 1250*16 == 20000

    for (int e = tid; e < PTS_B * 64; e += 512)
        pe_buf[(e >> 6) * PADPE + (e & 63)] = (_Float16)1.0f;

    const int n0 = nb + wave * 2, n1 = n0 + 1;
    int ik0 = 0, ik1 = 0; float dk0 = 0.f, dk1 = 0.f;
    if (lane < KNN) {
        ik0 = oidx[n0 * KNN + lane]; dk0 = odist[n0 * KNN + lane];
        ik1 = oidx[n1 * KNN + lane]; dk1 = odist[n1 * KNN + lane];
    }
    float pe_res0 = 1.f, pe_res1 = 1.f;
    __syncthreads();

    for (int l = 0; l < NLAYERS; ++l) {
        if (l) __syncthreads();                    // GN msg-reads done; pe_buf visible
        const float* Wl  = W1 + (size_t)l * HID * HID;
        const float* W2l = W2 + (size_t)l * HID * DAT;
        const _Float16* Al = A + (size_t)l * M_ATOMS * A_HSTRIDE;

        // issue A-gathers early (latency hidden under MFMA-1)
        half2_t Av0[KNN], Av1[KNN];
#pragma unroll
        for (int k = 0; k < KNN; ++k) {
            int i0 = __builtin_amdgcn_readlane(ik0, k);
            int i1 = __builtin_amdgcn_readlane(ik1, k);
            Av0[k] = ((const half2_t*)(Al + (size_t)i0 * A_HSTRIDE))[lane];
            Av1[k] = ((const half2_t*)(Al + (size_t)i1 * A_HSTRIDE))[lane];
        }
        float A20 = 0.f, A21 = 0.f;
        if (lane < KNN) {
            A20 = (float)Al[(size_t)ik0 * A_HSTRIDE + 128];
            A21 = (float)Al[(size_t)ik1 * A_HSTRIDE + 128];
        }

        // MFMA-1: P[16][129] = pe[16][64] @ W1[0:64][129]  (9 N-tiles x 2 K)
        {
            const f16x8* w1p = (const f16x8*)(w1fg + (size_t)l * W1F_HALVES);
            for (int t = wave; t < 9; t += 8) {
                f32x4 acc = {0.f, 0.f, 0.f, 0.f};
#pragma unroll
                for (int kk = 0; kk < 2; ++kk) {
                    f16x8 a = *(const f16x8*)&pe_buf[lr * PADPE + kk * 32 + lg * 8];
                    f16x8 b = w1p[(kk * 4 + lg) * 144 + t * 16 + lr];
                    acc = __builtin_amdgcn_mfma_f32_16x16x32_f16(a, b, acc, 0, 0, 0);
                }
#pragma unroll
                for (int r = 0; r < 4; ++r)
                    Pms[(lg * 4 + r) * PADP + t * 16 + lr] = acc[r];
            }
        }
        __syncthreads();

        // hsum: wave owns points 2w, 2w+1; lane owns channels (2l, 2l+1)
        {
            const float wl0 = Wl[128 * HID + 2 * lane];
            const float wl1 = Wl[128 * HID + 2 * lane + 1];
            const float wl2 = Wl[128 * HID + 128];
#pragma unroll
            for (int p = 0; p < 2; ++p) {
                const int nl = wave * 2 + p;
                const half2_t* Av = p ? Av1 : Av0;
                const float A2l = p ? A21 : A20;
                const float dkl = p ? dk1 : dk0;
                float2 pp = *(const float2*)&Pms[nl * PADP + 2 * lane];
                float p2  = Pms[nl * PADP + 128];
                float hs0 = 0.f, hs1 = 0.f, hs2 = 0.f;
#pragma unroll
                for (int k = 0; k < KNN; ++k) {
                    float dd = readlane_f(dkl, k);
                    float a2 = readlane_f(A2l, k);
                    float h0 = pp.x + (float)Av[k].x + dd * wl0; hs0 += fmaxf(h0, 0.2f * h0);
                    float h1 = pp.y + (float)Av[k].y + dd * wl1; hs1 += fmaxf(h1, 0.2f * h1);
                    float h2 = p2   + a2             + dd * wl2; hs2 += fmaxf(h2, 0.2f * h2);
                }
                half2_t hv; hv.x = (_Float16)hs0; hv.y = (_Float16)hs1;
                *(half2_t*)&hs_lds[nl * PADHS + 2 * lane] = hv;
                if (lane == 0) hs2_lds[nl] = hs2;
            }
        }
        __syncthreads();

        // MFMA-2: MSG[16][64] = HS[16][128] @ W2[0:128][64]  (4 N-tiles x 4 K; waves 0-3)
        if (wave < 4) {
            const f16x8* w2p = (const f16x8*)(w2fg + (size_t)l * W2F_HALVES);
            f32x4 acc = {0.f, 0.f, 0.f, 0.f};
#pragma unroll
            for (int kk = 0; kk < 4; ++kk) {
                f16x8 a = *(const f16x8*)&hs_lds[lr * PADHS + kk * 32 + lg * 8];
                f16x8 b = w2p[(kk * 4 + lg) * 64 + wave * 16 + lr];
                acc = __builtin_amdgcn_mfma_f32_16x16x32_f16(a, b, acc, 0, 0, 0);
            }
#pragma unroll
            for (int r = 0; r < 4; ++r)
                Pms[(lg * 4 + r) * PADMS + wave * 16 + lr] = acc[r];   // MSG region
        }
        __syncthreads();

        // GroupNorm + leaky + residual: wave owns points 2w, 2w+1; lane = channel
        {
            const float w2c = W2l[128 * DAT + lane];
            const float b2v = 16.f * b2[l * DAT + lane];
            const float gw  = gnw[l * DAT + lane], gb = gnb[l * DAT + lane];
#pragma unroll
            for (int p = 0; p < 2; ++p) {
                const int nl = wave * 2 + p;
                float pe = p ? pe_res1 : pe_res0;
                float m = Pms[nl * PADMS + lane] + hs2_lds[nl] * w2c + b2v;
                float s1 = m;
                s1 += __shfl_xor(s1, 1);  s1 += __shfl_xor(s1, 2);  s1 += __shfl_xor(s1, 4);
                s1 += __shfl_xor(s1, 8);  s1 += __shfl_xor(s1, 16);
                float mu = s1 * (1.f / 32.f);
                float dm = m - mu;
                float s2 = dm * dm;
                s2 += __shfl_xor(s2, 1);  s2 += __shfl_xor(s2, 2);  s2 += __shfl_xor(s2, 4);
                s2 += __shfl_xor(s2, 8);  s2 += __shfl_xor(s2, 16);
                float var = s2 * (1.f / 32.f);
                float g = dm * (1.f / sqrtf(var + 1e-5f)) * gw + gb;
                pe += fmaxf(g, 0.2f * g);
                if (p) pe_res1 = pe; else pe_res0 = pe;
                if (l == NLAYERS - 1) out[(nb + nl) * DAT + lane] = pe;
                else                  pe_buf[nl * PADPE + lane] = (_Float16)pe;
            }
        }
    }
}

// ---------------- launch ----------------
extern "C" void kernel_launch(void* const* d_in, const int* in_sizes, int n_in,
                              void* d_out, int out_size, void* d_ws, size_t ws_size,
                              hipStream_t stream) {
    const float* x     = (const float*)d_in[0];
    const float* y     = (const float*)d_in[1];
    const float* feats = (const float*)d_in[2];
    const float* W1    = (const float*)d_in[3];
    const float* b1    = (const float*)d_in[4];
    const float* W2    = (const float*)d_in[5];
    const float* b2    = (const float*)d_in[6];
    const float* gnw   = (const float*)d_in[7];
    const float* gnb   = (const float*)d_in[8];
    float* out = (float*)d_out;

    char* ws = (char*)d_ws;
    float4*    ypc   = (float4*)  ws;                        // 160,000 B
    int*       oidx  = (int*)    (ws + 160000);              // 1,280,000 B
    float*     odist = (float*)  (ws + 1440000);             // 1,280,000 B
    _Float16*  A     = (_Float16*)(ws + 2720000);            // 7,920,000 B
    int*       starts= (int*)    (ws + 10640000);            // (13824+1)*4
    int*       cursor= (int*)    (ws + 10700000);            // 13824*4
    int*       counts= (int*)    (ws + 10760000);            // (13824+1)*4
    int*       acell = (int*)    (ws + 10820000);            // 10000*4
    int*       aidx  = (int*)    (ws + 10860000);            // 10000*4
    _Float16*  w1fg  = (_Float16*)(ws + 10900000);           // 3*9216*2 = 55,296 B
    _Float16*  w2fg  = (_Float16*)(ws + 10955296);           // 3*8192*2 = 49,152 B
    // total ~11.0 MB of ws

    wfrag_kernel<<<dim3((NLAYERS * (W1F_HALVES + W2F_HALVES) + 511) / 512), dim3(512), 0, stream>>>(W1, W2, w1fg, w2fg);
    grid_zero   <<<dim3((NCELL + 256) / 256), dim3(256), 0, stream>>>(counts);
    grid_count  <<<dim3((M_ATOMS + 255) / 256), dim3(256), 0, stream>>>(y, counts, acell);
    grid_scan   <<<dim3(1), dim3(1024), 0, stream>>>(counts, starts, cursor);
    grid_scatter<<<dim3((M_ATOMS + 255) / 256), dim3(256), 0, stream>>>(y, acell, cursor, ypc, aidx);
    knn_pre     <<<dim3(KNN_NBLK + PRE_NBLK), dim3(256), 0, stream>>>(
                    x, y, starts, ypc, aidx, oidx, odist, feats, W1, b1, A);
    mlp_mfma    <<<dim3(N_PTS / PTS_B), dim3(512), 0, stream>>>(
                    W1, W2, b2, gnw, gnb, A, w1fg, w2fg, oidx, odist, out);
}